// Round 1
// baseline (648.536 us; speedup 1.0000x reference)
//
#include <hip/hip_runtime.h>
#include <hip/hip_bf16.h>

#define N_EXPERTS 8
#define EMB 1024
#define HID 2816
#define NTOK 4096
#define NSLOT (NTOK * 2)
#define TLIST NTOK

typedef float f32x4 __attribute__((ext_vector_type(4)));
typedef short short8 __attribute__((ext_vector_type(8)));

static __device__ __forceinline__ unsigned short f2bf(float v) {
    __hip_bfloat16 b = __float2bfloat16(v);
    return *reinterpret_cast<unsigned short*>(&b);
}

// async global->LDS, 16B per lane. LDS dest = wave-uniform base + lane*16.
static __device__ __forceinline__ void ldst16(const unsigned short* g, unsigned short* l) {
    __builtin_amdgcn_global_load_lds(
        (const __attribute__((address_space(1))) unsigned int*)g,
        (__attribute__((address_space(3))) unsigned int*)l,
        16, 0, 0);
}

// ---------- fused weight transpose + fp32->bf16 for all three weights ----------
// z in [0,24): which = z>>3 (0:w1, 1:w3, 2:w2), e = z&7.
// w1/w3: R=EMB (y tiles, 16), C=HID (x tiles, 44).
// w2:    R=HID (x tiles, 44), C=EMB (y tiles, 16)  (roles swapped to share the grid).
__global__ __launch_bounds__(256) void transpose_cvt_all(const float* __restrict__ w1,
                                                         const float* __restrict__ w3,
                                                         const float* __restrict__ w2,
                                                         unsigned short* __restrict__ w1T,
                                                         unsigned short* __restrict__ w3T,
                                                         unsigned short* __restrict__ w2T) {
    __shared__ unsigned short tile[64][68];
    int z = blockIdx.z;
    int which = z >> 3, e = z & 7;
    const float* in;
    unsigned short* out;
    int R, C, r0, c0;
    if (which == 0)      { in = w1; out = w1T; R = EMB; C = HID; r0 = blockIdx.y * 64; c0 = blockIdx.x * 64; }
    else if (which == 1) { in = w3; out = w3T; R = EMB; C = HID; r0 = blockIdx.y * 64; c0 = blockIdx.x * 64; }
    else                 { in = w2; out = w2T; R = HID; C = EMB; r0 = blockIdx.x * 64; c0 = blockIdx.y * 64; }
    const float* src = in + (size_t)e * R * C;
    unsigned short* dst = out + (size_t)e * R * C;
    int tid = threadIdx.x;
#pragma unroll
    for (int i = 0; i < 4; ++i) {
        int lin = i * 256 + tid;
        int r = lin >> 4, c4 = (lin & 15) * 4;
        float4 v = *(const float4*)&src[(size_t)(r0 + r) * C + c0 + c4];
        ushort4 b;
        b.x = f2bf(v.x); b.y = f2bf(v.y); b.z = f2bf(v.z); b.w = f2bf(v.w);
        *(ushort4*)&tile[r][c4] = b;
    }
    __syncthreads();
#pragma unroll
    for (int i = 0; i < 4; ++i) {
        int lin = i * 256 + tid;
        int c = lin >> 4, r4 = (lin & 15) * 4;
        ushort4 b;
        b.x = tile[r4 + 0][c]; b.y = tile[r4 + 1][c];
        b.z = tile[r4 + 2][c]; b.w = tile[r4 + 3][c];
        *(ushort4*)&dst[(size_t)(c0 + c) * R + r0 + r4] = b;
    }
}

// ---------- zero the output (gemm2 accumulates into it with atomics) ----------
__global__ __launch_bounds__(256) void zero_out(float* __restrict__ p) {
    int gid = blockIdx.x * 256 + threadIdx.x;
    float4 z = {0.f, 0.f, 0.f, 0.f};
    ((float4*)p)[gid] = z;
}

// ---------- router: fp32 scores, top-2 softmax -> sel + gates; x -> bf16. NO atomics. ----------
__global__ __launch_bounds__(64) void router_kernel(const float* __restrict__ x,
                                                    const float* __restrict__ wr,
                                                    unsigned short* __restrict__ xbf,
                                                    int* __restrict__ sel,
                                                    float* __restrict__ gates) {
    int t = blockIdx.x, lane = threadIdx.x;
    const float* xr = x + (size_t)t * EMB;
    float acc[N_EXPERTS];
#pragma unroll
    for (int e = 0; e < N_EXPERTS; ++e) acc[e] = 0.f;
    for (int d = lane; d < EMB; d += 64) {
        float xv = xr[d];
        xbf[(size_t)t * EMB + d] = f2bf(xv);
        const float* w = wr + d * N_EXPERTS;
#pragma unroll
        for (int e = 0; e < N_EXPERTS; ++e) acc[e] += xv * w[e];
    }
#pragma unroll
    for (int off = 32; off; off >>= 1) {
#pragma unroll
        for (int e = 0; e < N_EXPERTS; ++e) acc[e] += __shfl_xor(acc[e], off, 64);
    }
    if (lane == 0) {
        int b0 = 0; float v0 = acc[0];
#pragma unroll
        for (int e = 1; e < N_EXPERTS; ++e) if (acc[e] > v0) { v0 = acc[e]; b0 = e; }
        int b1 = -1; float v1 = -1e30f;
#pragma unroll
        for (int e = 0; e < N_EXPERTS; ++e) if (e != b0 && acc[e] > v1) { v1 = acc[e]; b1 = e; }
        float g0 = 1.f / (1.f + expf(v1 - v0));
        float g1 = 1.f - g0;
        sel[t] = b0 | (b1 << 8);
        gates[2 * t] = g0;
        gates[2 * t + 1] = g1;
    }
}

// ---------- deterministic list build: one block per expert, ordered ballot compaction ----------
__global__ __launch_bounds__(256) void build_lists(const int* __restrict__ sel,
                                                   int* __restrict__ counts,
                                                   int* __restrict__ lists) {
    int e = blockIdx.x;
    int tid = threadIdx.x, lane = tid & 63, wid = tid >> 6;
    __shared__ int wsum[4];
    __shared__ int running;
    if (tid == 0) running = 0;
    __syncthreads();
    for (int base = 0; base < NTOK; base += 256) {
        int tok = base + tid;
        int s = sel[tok];
        int e0 = s & 0xff, e1 = (s >> 8) & 0xff;
        bool take = (e0 == e) || (e1 == e);
        int slot = (e0 == e) ? 2 * tok : 2 * tok + 1;
        unsigned long long b = __ballot(take);
        int lp = __popcll(b & ((1ull << lane) - 1ull));
        if (lane == 0) wsum[wid] = __popcll(b);
        __syncthreads();
        int off = running;
        for (int w = 0; w < wid; ++w) off += wsum[w];
        if (take) lists[e * TLIST + off + lp] = slot;
        __syncthreads();
        if (tid == 0) running += wsum[0] + wsum[1] + wsum[2] + wsum[3];
        __syncthreads();
    }
    if (tid == 0) counts[e] = running;
}

// ---------- GEMM1: h[slot] = silu(x@w1) * (x@w3), bf16 out ----------
// Double-buffered, prefetched pipeline: stage(t+1) issued BEFORE compute(t),
// single __syncthreads per K-step (its implicit vmcnt(0)+lgkmcnt(0) drain is the fence).
__global__ __launch_bounds__(256) void gemm1_kernel(const unsigned short* __restrict__ xbf,
                                                    const unsigned short* __restrict__ w1T,
                                                    const unsigned short* __restrict__ w3T,
                                                    unsigned short* __restrict__ h,
                                                    const int* __restrict__ counts,
                                                    const int* __restrict__ lists) {
    int e = blockIdx.z;
    int cnt = counts[e];
    int rt = blockIdx.y;
    if (rt * 128 >= cnt) return;
    int n0 = blockIdx.x * 64;

    __shared__ unsigned short As[2][128 * 32];
    __shared__ unsigned short B1s[2][64 * 32];
    __shared__ unsigned short B3s[2][64 * 32];
    __shared__ int slotArr[128];

    int tid = threadIdx.x;
    if (tid < 128) {
        int r = rt * 128 + tid;
        slotArr[tid] = (r < cnt) ? lists[e * TLIST + r] : -1;
    }
    __syncthreads();

    int lane = tid & 63, wid = tid >> 6;
    int seg = lane >> 2, chunk = lane & 3;

    int rA0 = wid * 32 + seg, rA1 = wid * 32 + 16 + seg;
    int s0 = slotArr[rA0], s1 = slotArr[rA1];
    int t0 = s0 >= 0 ? (s0 >> 1) : 0, t1 = s1 >= 0 ? (s1 >> 1) : 0;
    const unsigned short* gA0 = xbf + (size_t)t0 * EMB + chunk * 8;
    const unsigned short* gA1 = xbf + (size_t)t1 * EMB + chunk * 8;
    int rB = n0 + wid * 16 + seg;
    const unsigned short* gB1 = w1T + ((size_t)e * HID + rB) * EMB + chunk * 8;
    const unsigned short* gB3 = w3T + ((size_t)e * HID + rB) * EMB + chunk * 8;
    unsigned short* lA0 = &As[0][wid * 1024];
    unsigned short* lA1 = &As[0][wid * 1024 + 512];
    unsigned short* lB1 = &B1s[0][wid * 512];
    unsigned short* lB3 = &B3s[0][wid * 512];
    const int DA = 128 * 32;   // short stride between As buffers
    const int DB = 64 * 32;    // short stride between B buffers

    int wr = wid >> 1, wc = wid & 1;
    int lrow = lane & 15, quad = lane >> 4;

    f32x4 zero4 = {0.f, 0.f, 0.f, 0.f};
    f32x4 acc1[4][2], acc3[4][2];
#pragma unroll
    for (int mt = 0; mt < 4; ++mt)
#pragma unroll
        for (int nt = 0; nt < 2; ++nt) { acc1[mt][nt] = zero4; acc3[mt][nt] = zero4; }

#define G1_COMPUTE(b) do {                                                                  \
        short8 af[4], b1f[2], b3f[2];                                                       \
        _Pragma("unroll")                                                                   \
        for (int mt = 0; mt < 4; ++mt)                                                      \
            af[mt] = *(const short8*)&As[b][(wr * 64 + mt * 16 + lrow) * 32 + quad * 8];    \
        _Pragma("unroll")                                                                   \
        for (int nt = 0; nt < 2; ++nt) {                                                    \
            b1f[nt] = *(const short8*)&B1s[b][(wc * 32 + nt * 16 + lrow) * 32 + quad * 8];  \
            b3f[nt] = *(const short8*)&B3s[b][(wc * 32 + nt * 16 + lrow) * 32 + quad * 8];  \
        }                                                                                   \
        _Pragma("unroll")                                                                   \
        for (int mt = 0; mt < 4; ++mt)                                                      \
            _Pragma("unroll")                                                               \
            for (int nt = 0; nt < 2; ++nt) {                                                \
                acc1[mt][nt] = __builtin_amdgcn_mfma_f32_16x16x32_bf16(af[mt], b1f[nt], acc1[mt][nt], 0, 0, 0); \
                acc3[mt][nt] = __builtin_amdgcn_mfma_f32_16x16x32_bf16(af[mt], b3f[nt], acc3[mt][nt], 0, 0, 0); \
            }                                                                               \
    } while (0)

    // prologue: stage k-step 0 into buf0
    ldst16(gA0, lA0); ldst16(gA1, lA1); ldst16(gB1, lB1); ldst16(gB3, lB3);
    gA0 += 32; gA1 += 32; gB1 += 32; gB3 += 32;
    __syncthreads();

    const int KT = EMB / 32;     // 32, even
    for (int kt = 0; kt < KT; kt += 2) {
        // prefetch kt+1 into buf1, then compute buf0
        ldst16(gA0, lA0 + DA); ldst16(gA1, lA1 + DA);
        ldst16(gB1, lB1 + DB); ldst16(gB3, lB3 + DB);
        gA0 += 32; gA1 += 32; gB1 += 32; gB3 += 32;
        G1_COMPUTE(0);
        __syncthreads();
        // prefetch kt+2 into buf0 (if any), then compute buf1
        if (kt + 2 < KT) {
            ldst16(gA0, lA0); ldst16(gA1, lA1);
            ldst16(gB1, lB1); ldst16(gB3, lB3);
            gA0 += 32; gA1 += 32; gB1 += 32; gB3 += 32;
        }
        G1_COMPUTE(1);
        __syncthreads();
    }
#undef G1_COMPUTE

#pragma unroll
    for (int mt = 0; mt < 4; ++mt) {
#pragma unroll
        for (int i = 0; i < 4; ++i) {
            int r = wr * 64 + mt * 16 + quad * 4 + i;
            int slot = slotArr[r];
            if (slot < 0) continue;
#pragma unroll
            for (int nt = 0; nt < 2; ++nt) {
                float v1 = acc1[mt][nt][i];
                float v3 = acc3[mt][nt][i];
                float hv = v1 / (1.f + __expf(-v1)) * v3;
                int c = n0 + wc * 32 + nt * 16 + lrow;
                h[(size_t)slot * HID + c] = f2bf(hv);
            }
        }
    }
}

// ---------- GEMM2: out[tok] += gate[slot] * (h[slot] @ w2)  (fp32 atomicAdd, exactly 2 adds/elem) ----------
__global__ __launch_bounds__(256) void gemm2_kernel(const unsigned short* __restrict__ h,
                                                    const unsigned short* __restrict__ w2T,
                                                    float* __restrict__ out,
                                                    const int* __restrict__ counts,
                                                    const int* __restrict__ lists,
                                                    const float* __restrict__ gates) {
    int e = blockIdx.z;
    int cnt = counts[e];
    int rt = blockIdx.y;
    if (rt * 128 >= cnt) return;
    int n0 = blockIdx.x * 128;

    __shared__ unsigned short As[2][128 * 32];
    __shared__ unsigned short Bs[2][128 * 32];
    __shared__ int slotArr[128];

    int tid = threadIdx.x;
    if (tid < 128) {
        int r = rt * 128 + tid;
        slotArr[tid] = (r < cnt) ? lists[e * TLIST + r] : -1;
    }
    __syncthreads();

    int lane = tid & 63, wid = tid >> 6;
    int seg = lane >> 2, chunk = lane & 3;

    int rA0 = wid * 32 + seg, rA1 = wid * 32 + 16 + seg;
    int s0 = slotArr[rA0], s1 = slotArr[rA1];
    const unsigned short* gA0 = h + (size_t)(s0 < 0 ? 0 : s0) * HID + chunk * 8;
    const unsigned short* gA1 = h + (size_t)(s1 < 0 ? 0 : s1) * HID + chunk * 8;
    int rB0 = n0 + wid * 32 + seg, rB1 = rB0 + 16;
    const unsigned short* gB0 = w2T + ((size_t)e * EMB + rB0) * HID + chunk * 8;
    const unsigned short* gB1 = w2T + ((size_t)e * EMB + rB1) * HID + chunk * 8;
    unsigned short* lA0 = &As[0][wid * 1024];
    unsigned short* lA1 = &As[0][wid * 1024 + 512];
    unsigned short* lB0 = &Bs[0][wid * 1024];
    unsigned short* lB1 = &Bs[0][wid * 1024 + 512];
    const int D2 = 128 * 32;   // short stride between buffers

    int wr = wid >> 1, wc = wid & 1;
    int lrow = lane & 15, quad = lane >> 4;

    f32x4 zero4 = {0.f, 0.f, 0.f, 0.f};
    f32x4 acc[4][4];
#pragma unroll
    for (int mt = 0; mt < 4; ++mt)
#pragma unroll
        for (int nt = 0; nt < 4; ++nt) acc[mt][nt] = zero4;

#define G2_COMPUTE(b) do {                                                                  \
        short8 af[4], bf[4];                                                                \
        _Pragma("unroll")                                                                   \
        for (int mt = 0; mt < 4; ++mt)                                                      \
            af[mt] = *(const short8*)&As[b][(wr * 64 + mt * 16 + lrow) * 32 + quad * 8];    \
        _Pragma("unroll")                                                                   \
        for (int nt = 0; nt < 4; ++nt)                                                      \
            bf[nt] = *(const short8*)&Bs[b][(wc * 64 + nt * 16 + lrow) * 32 + quad * 8];    \
        _Pragma("unroll")                                                                   \
        for (int mt = 0; mt < 4; ++mt)                                                      \
            _Pragma("unroll")                                                               \
            for (int nt = 0; nt < 4; ++nt)                                                  \
                acc[mt][nt] = __builtin_amdgcn_mfma_f32_16x16x32_bf16(af[mt], bf[nt], acc[mt][nt], 0, 0, 0); \
    } while (0)

    // prologue
    ldst16(gA0, lA0); ldst16(gA1, lA1); ldst16(gB0, lB0); ldst16(gB1, lB1);
    gA0 += 32; gA1 += 32; gB0 += 32; gB1 += 32;
    __syncthreads();

    const int KT = HID / 32;   // 88, even
    for (int kt = 0; kt < KT; kt += 2) {
        ldst16(gA0, lA0 + D2); ldst16(gA1, lA1 + D2);
        ldst16(gB0, lB0 + D2); ldst16(gB1, lB1 + D2);
        gA0 += 32; gA1 += 32; gB0 += 32; gB1 += 32;
        G2_COMPUTE(0);
        __syncthreads();
        if (kt + 2 < KT) {
            ldst16(gA0, lA0); ldst16(gA1, lA1);
            ldst16(gB0, lB0); ldst16(gB1, lB1);
            gA0 += 32; gA1 += 32; gB0 += 32; gB1 += 32;
        }
        G2_COMPUTE(1);
        __syncthreads();
    }
#undef G2_COMPUTE

#pragma unroll
    for (int mt = 0; mt < 4; ++mt) {
#pragma unroll
        for (int i = 0; i < 4; ++i) {
            int r = wr * 64 + mt * 16 + quad * 4 + i;
            int slot = slotArr[r];
            if (slot < 0) continue;
            float g = gates[slot];
            int tok = slot >> 1;
#pragma unroll
            for (int nt = 0; nt < 4; ++nt) {
                int c = n0 + wc * 64 + nt * 16 + lrow;
                atomicAdd(&out[(size_t)tok * EMB + c], g * acc[mt][nt][i]);
            }
        }
    }
}

extern "C" void kernel_launch(void* const* d_in, const int* in_sizes, int n_in,
                              void* d_out, int out_size, void* d_ws, size_t ws_size,
                              hipStream_t stream) {
    const float* x = (const float*)d_in[0];
    const float* wrout = (const float*)d_in[1];
    const float* w1 = (const float*)d_in[2];
    const float* w3 = (const float*)d_in[3];
    const float* w2 = (const float*)d_in[4];
    float* out = (float*)d_out;

    char* ws = (char*)d_ws;
    const size_t SW = (size_t)N_EXPERTS * EMB * HID * 2;
    const size_t SX = (size_t)NTOK * EMB * 2;
    const size_t SH = (size_t)NSLOT * HID * 2;
    const size_t SMETA = 256 + (size_t)N_EXPERTS * TLIST * 4 + (size_t)NSLOT * 4 + (size_t)NTOK * 4;
    const size_t NEEDED = 3 * SW + SX + SH + SMETA;
    if (ws_size < NEEDED) return;

    unsigned short* w1T = (unsigned short*)(ws);
    unsigned short* w3T = (unsigned short*)(ws + SW);
    unsigned short* w2T = (unsigned short*)(ws + 2 * SW);
    unsigned short* xbf = (unsigned short*)(ws + 3 * SW);
    unsigned short* hbuf = (unsigned short*)(ws + 3 * SW + SX);
    char* meta = ws + 3 * SW + SX + SH;
    int* counts = (int*)meta;
    int* lists = (int*)(meta + 256);
    float* gates = (float*)(meta + 256 + (size_t)N_EXPERTS * TLIST * 4);
    int* sel = (int*)(meta + 256 + (size_t)N_EXPERTS * TLIST * 4 + (size_t)NSLOT * 4);

    // one launch for all three weight transposes (w1:z 0-7, w3:z 8-15, w2:z 16-23)
    transpose_cvt_all<<<dim3(HID / 64, EMB / 64, 3 * N_EXPERTS), 256, 0, stream>>>(
        w1, w3, w2, w1T, w3T, w2T);

    zero_out<<<NTOK * EMB / 4 / 256, 256, 0, stream>>>(out);

    router_kernel<<<NTOK, 64, 0, stream>>>(x, wrout, xbf, sel, gates);
    build_lists<<<N_EXPERTS, 256, 0, stream>>>(sel, counts, lists);

    gemm1_kernel<<<dim3(HID / 64, NTOK / 128, N_EXPERTS), 256, 0, stream>>>(
        xbf, w1T, w3T, hbuf, counts, lists);
    gemm2_kernel<<<dim3(EMB / 128, NTOK / 128, N_EXPERTS), 256, 0, stream>>>(
        hbuf, w2T, out, counts, lists, gates);
}

// Round 2
// 552.313 us; speedup vs baseline: 1.1742x; 1.1742x over previous
//
#include <hip/hip_runtime.h>
#include <hip/hip_bf16.h>

#define N_EXPERTS 8
#define EMB 1024
#define HID 2816
#define NTOK 4096
#define NSLOT (NTOK * 2)
#define TLIST NTOK

typedef float f32x4 __attribute__((ext_vector_type(4)));
typedef short short8 __attribute__((ext_vector_type(8)));

static __device__ __forceinline__ unsigned short f2bf(float v) {
    __hip_bfloat16 b = __float2bfloat16(v);
    return *reinterpret_cast<unsigned short*>(&b);
}

// async global->LDS, 16B per lane. LDS dest = wave-uniform base + lane*16.
static __device__ __forceinline__ void ldst16(const unsigned short* g, unsigned short* l) {
    __builtin_amdgcn_global_load_lds(
        (const __attribute__((address_space(1))) unsigned int*)g,
        (__attribute__((address_space(3))) unsigned int*)l,
        16, 0, 0);
}

// ---------- fused weight transpose + fp32->bf16 for all three weights ----------
// z in [0,24): which = z>>3 (0:w1, 1:w3, 2:w2), e = z&7.
// w1/w3: R=EMB, C=HID. w2: R=HID, C=EMB (x/y tile roles swapped to share the grid).
__global__ __launch_bounds__(256) void transpose_cvt_all(const float* __restrict__ w1,
                                                         const float* __restrict__ w3,
                                                         const float* __restrict__ w2,
                                                         unsigned short* __restrict__ w1T,
                                                         unsigned short* __restrict__ w3T,
                                                         unsigned short* __restrict__ w2T) {
    __shared__ unsigned short tile[64][68];
    int z = blockIdx.z;
    int which = z >> 3, e = z & 7;
    const float* in;
    unsigned short* out;
    int R, C, r0, c0;
    if (which == 0)      { in = w1; out = w1T; R = EMB; C = HID; r0 = blockIdx.y * 64; c0 = blockIdx.x * 64; }
    else if (which == 1) { in = w3; out = w3T; R = EMB; C = HID; r0 = blockIdx.y * 64; c0 = blockIdx.x * 64; }
    else                 { in = w2; out = w2T; R = HID; C = EMB; r0 = blockIdx.x * 64; c0 = blockIdx.y * 64; }
    const float* src = in + (size_t)e * R * C;
    unsigned short* dst = out + (size_t)e * R * C;
    int tid = threadIdx.x;
#pragma unroll
    for (int i = 0; i < 4; ++i) {
        int lin = i * 256 + tid;
        int r = lin >> 4, c4 = (lin & 15) * 4;
        float4 v = *(const float4*)&src[(size_t)(r0 + r) * C + c0 + c4];
        ushort4 b;
        b.x = f2bf(v.x); b.y = f2bf(v.y); b.z = f2bf(v.z); b.w = f2bf(v.w);
        *(ushort4*)&tile[r][c4] = b;
    }
    __syncthreads();
#pragma unroll
    for (int i = 0; i < 4; ++i) {
        int lin = i * 256 + tid;
        int c = lin >> 4, r4 = (lin & 15) * 4;
        ushort4 b;
        b.x = tile[r4 + 0][c]; b.y = tile[r4 + 1][c];
        b.z = tile[r4 + 2][c]; b.w = tile[r4 + 3][c];
        *(ushort4*)&dst[(size_t)(c0 + c) * R + r0 + r4] = b;
    }
}

// ---------- zero the output (gemm2 accumulates into it with atomics) ----------
__global__ __launch_bounds__(256) void zero_out(float* __restrict__ p) {
    int gid = blockIdx.x * 256 + threadIdx.x;
    float4 z = {0.f, 0.f, 0.f, 0.f};
    ((float4*)p)[gid] = z;
}

// ---------- router: fp32 scores, top-2 softmax -> sel + gates; x -> bf16. NO atomics. ----------
__global__ __launch_bounds__(64) void router_kernel(const float* __restrict__ x,
                                                    const float* __restrict__ wr,
                                                    unsigned short* __restrict__ xbf,
                                                    int* __restrict__ sel,
                                                    float* __restrict__ gates) {
    int t = blockIdx.x, lane = threadIdx.x;
    const float* xr = x + (size_t)t * EMB;
    float acc[N_EXPERTS];
#pragma unroll
    for (int e = 0; e < N_EXPERTS; ++e) acc[e] = 0.f;
    for (int d = lane; d < EMB; d += 64) {
        float xv = xr[d];
        xbf[(size_t)t * EMB + d] = f2bf(xv);
        const float* w = wr + d * N_EXPERTS;
#pragma unroll
        for (int e = 0; e < N_EXPERTS; ++e) acc[e] += xv * w[e];
    }
#pragma unroll
    for (int off = 32; off; off >>= 1) {
#pragma unroll
        for (int e = 0; e < N_EXPERTS; ++e) acc[e] += __shfl_xor(acc[e], off, 64);
    }
    if (lane == 0) {
        int b0 = 0; float v0 = acc[0];
#pragma unroll
        for (int e = 1; e < N_EXPERTS; ++e) if (acc[e] > v0) { v0 = acc[e]; b0 = e; }
        int b1 = -1; float v1 = -1e30f;
#pragma unroll
        for (int e = 0; e < N_EXPERTS; ++e) if (e != b0 && acc[e] > v1) { v1 = acc[e]; b1 = e; }
        float g0 = 1.f / (1.f + expf(v1 - v0));
        float g1 = 1.f - g0;
        sel[t] = b0 | (b1 << 8);
        gates[2 * t] = g0;
        gates[2 * t + 1] = g1;
    }
}

// ---------- deterministic list build: one block per expert, ordered ballot compaction ----------
__global__ __launch_bounds__(256) void build_lists(const int* __restrict__ sel,
                                                   int* __restrict__ counts,
                                                   int* __restrict__ lists) {
    int e = blockIdx.x;
    int tid = threadIdx.x, lane = tid & 63, wid = tid >> 6;
    __shared__ int wsum[4];
    __shared__ int running;
    if (tid == 0) running = 0;
    __syncthreads();
    for (int base = 0; base < NTOK; base += 256) {
        int tok = base + tid;
        int s = sel[tok];
        int e0 = s & 0xff, e1 = (s >> 8) & 0xff;
        bool take = (e0 == e) || (e1 == e);
        int slot = (e0 == e) ? 2 * tok : 2 * tok + 1;
        unsigned long long b = __ballot(take);
        int lp = __popcll(b & ((1ull << lane) - 1ull));
        if (lane == 0) wsum[wid] = __popcll(b);
        __syncthreads();
        int off = running;
        for (int w = 0; w < wid; ++w) off += wsum[w];
        if (take) lists[e * TLIST + off + lp] = slot;
        __syncthreads();
        if (tid == 0) running += wsum[0] + wsum[1] + wsum[2] + wsum[3];
        __syncthreads();
    }
    if (tid == 0) counts[e] = running;
}

// ---------- GEMM1: h[slot] = silu(x@w1) * (x@w3), bf16 out ----------
// Proven round-0 structure: single LDS buffer, explicit drain + barrier per K-step.
__global__ __launch_bounds__(256) void gemm1_kernel(const unsigned short* __restrict__ xbf,
                                                    const unsigned short* __restrict__ w1T,
                                                    const unsigned short* __restrict__ w3T,
                                                    unsigned short* __restrict__ h,
                                                    const int* __restrict__ counts,
                                                    const int* __restrict__ lists) {
    int e = blockIdx.z;
    int cnt = counts[e];
    int rt = blockIdx.y;
    if (rt * 128 >= cnt) return;
    int n0 = blockIdx.x * 64;

    __shared__ unsigned short As[128 * 32];
    __shared__ unsigned short B1s[64 * 32];
    __shared__ unsigned short B3s[64 * 32];
    __shared__ int slotArr[128];

    int tid = threadIdx.x;
    if (tid < 128) {
        int r = rt * 128 + tid;
        slotArr[tid] = (r < cnt) ? lists[e * TLIST + r] : -1;
    }
    __syncthreads();

    int lane = tid & 63, wid = tid >> 6;
    int seg = lane >> 2, chunk = lane & 3;

    int rA0 = wid * 32 + seg, rA1 = wid * 32 + 16 + seg;
    int s0 = slotArr[rA0], s1 = slotArr[rA1];
    int t0 = s0 >= 0 ? (s0 >> 1) : 0, t1 = s1 >= 0 ? (s1 >> 1) : 0;
    const unsigned short* gA0 = xbf + (size_t)t0 * EMB + chunk * 8;
    const unsigned short* gA1 = xbf + (size_t)t1 * EMB + chunk * 8;
    int rB = n0 + wid * 16 + seg;
    const unsigned short* gB1 = w1T + ((size_t)e * HID + rB) * EMB + chunk * 8;
    const unsigned short* gB3 = w3T + ((size_t)e * HID + rB) * EMB + chunk * 8;
    unsigned short* lA0 = &As[wid * 1024];
    unsigned short* lA1 = &As[wid * 1024 + 512];
    unsigned short* lB1 = &B1s[wid * 512];
    unsigned short* lB3 = &B3s[wid * 512];

    int wr = wid >> 1, wc = wid & 1;
    int lrow = lane & 15, quad = lane >> 4;

    f32x4 zero4 = {0.f, 0.f, 0.f, 0.f};
    f32x4 acc1[4][2], acc3[4][2];
#pragma unroll
    for (int mt = 0; mt < 4; ++mt)
#pragma unroll
        for (int nt = 0; nt < 2; ++nt) { acc1[mt][nt] = zero4; acc3[mt][nt] = zero4; }

    const int KT = EMB / 32;
    for (int kt = 0; kt < KT; ++kt) {
        ldst16(gA0, lA0); ldst16(gA1, lA1);
        ldst16(gB1, lB1); ldst16(gB3, lB3);
        gA0 += 32; gA1 += 32; gB1 += 32; gB3 += 32;
        __builtin_amdgcn_s_waitcnt(0);   // explicit drain of global_load_lds before barrier
        __syncthreads();
        short8 af[4], b1f[2], b3f[2];
#pragma unroll
        for (int mt = 0; mt < 4; ++mt)
            af[mt] = *(const short8*)&As[(wr * 64 + mt * 16 + lrow) * 32 + quad * 8];
#pragma unroll
        for (int nt = 0; nt < 2; ++nt) {
            b1f[nt] = *(const short8*)&B1s[(wc * 32 + nt * 16 + lrow) * 32 + quad * 8];
            b3f[nt] = *(const short8*)&B3s[(wc * 32 + nt * 16 + lrow) * 32 + quad * 8];
        }
#pragma unroll
        for (int mt = 0; mt < 4; ++mt)
#pragma unroll
            for (int nt = 0; nt < 2; ++nt) {
                acc1[mt][nt] = __builtin_amdgcn_mfma_f32_16x16x32_bf16(af[mt], b1f[nt], acc1[mt][nt], 0, 0, 0);
                acc3[mt][nt] = __builtin_amdgcn_mfma_f32_16x16x32_bf16(af[mt], b3f[nt], acc3[mt][nt], 0, 0, 0);
            }
        __syncthreads();
    }

#pragma unroll
    for (int mt = 0; mt < 4; ++mt) {
#pragma unroll
        for (int i = 0; i < 4; ++i) {
            int r = wr * 64 + mt * 16 + quad * 4 + i;
            int slot = slotArr[r];
            if (slot < 0) continue;
#pragma unroll
            for (int nt = 0; nt < 2; ++nt) {
                float v1 = acc1[mt][nt][i];
                float v3 = acc3[mt][nt][i];
                float hv = v1 / (1.f + __expf(-v1)) * v3;
                int c = n0 + wc * 32 + nt * 16 + lrow;
                h[(size_t)slot * HID + c] = f2bf(hv);
            }
        }
    }
}

// ---------- GEMM2: out[tok] += gate[slot] * (h[slot] @ w2)  (fp32 atomicAdd, exactly 2 adds/elem) ----------
__global__ __launch_bounds__(256) void gemm2_kernel(const unsigned short* __restrict__ h,
                                                    const unsigned short* __restrict__ w2T,
                                                    float* __restrict__ out,
                                                    const int* __restrict__ counts,
                                                    const int* __restrict__ lists,
                                                    const float* __restrict__ gates) {
    int e = blockIdx.z;
    int cnt = counts[e];
    int rt = blockIdx.y;
    if (rt * 128 >= cnt) return;
    int n0 = blockIdx.x * 128;

    __shared__ unsigned short As[128 * 32];
    __shared__ unsigned short Bs[128 * 32];
    __shared__ int slotArr[128];

    int tid = threadIdx.x;
    if (tid < 128) {
        int r = rt * 128 + tid;
        slotArr[tid] = (r < cnt) ? lists[e * TLIST + r] : -1;
    }
    __syncthreads();

    int lane = tid & 63, wid = tid >> 6;
    int seg = lane >> 2, chunk = lane & 3;

    int rA0 = wid * 32 + seg, rA1 = wid * 32 + 16 + seg;
    int s0 = slotArr[rA0], s1 = slotArr[rA1];
    const unsigned short* gA0 = h + (size_t)(s0 < 0 ? 0 : s0) * HID + chunk * 8;
    const unsigned short* gA1 = h + (size_t)(s1 < 0 ? 0 : s1) * HID + chunk * 8;
    int rB0 = n0 + wid * 32 + seg, rB1 = rB0 + 16;
    const unsigned short* gB0 = w2T + ((size_t)e * EMB + rB0) * HID + chunk * 8;
    const unsigned short* gB1 = w2T + ((size_t)e * EMB + rB1) * HID + chunk * 8;
    unsigned short* lA0 = &As[wid * 1024];
    unsigned short* lA1 = &As[wid * 1024 + 512];
    unsigned short* lB0 = &Bs[wid * 1024];
    unsigned short* lB1 = &Bs[wid * 1024 + 512];

    int wr = wid >> 1, wc = wid & 1;
    int lrow = lane & 15, quad = lane >> 4;

    f32x4 zero4 = {0.f, 0.f, 0.f, 0.f};
    f32x4 acc[4][4];
#pragma unroll
    for (int mt = 0; mt < 4; ++mt)
#pragma unroll
        for (int nt = 0; nt < 4; ++nt) acc[mt][nt] = zero4;

    const int KT = HID / 32;
    for (int kt = 0; kt < KT; ++kt) {
        ldst16(gA0, lA0); ldst16(gA1, lA1);
        ldst16(gB0, lB0); ldst16(gB1, lB1);
        gA0 += 32; gA1 += 32; gB0 += 32; gB1 += 32;
        __builtin_amdgcn_s_waitcnt(0);
        __syncthreads();
        short8 af[4], bf[4];
#pragma unroll
        for (int mt = 0; mt < 4; ++mt)
            af[mt] = *(const short8*)&As[(wr * 64 + mt * 16 + lrow) * 32 + quad * 8];
#pragma unroll
        for (int nt = 0; nt < 4; ++nt)
            bf[nt] = *(const short8*)&Bs[(wc * 64 + nt * 16 + lrow) * 32 + quad * 8];
#pragma unroll
        for (int mt = 0; mt < 4; ++mt)
#pragma unroll
            for (int nt = 0; nt < 4; ++nt)
                acc[mt][nt] = __builtin_amdgcn_mfma_f32_16x16x32_bf16(af[mt], bf[nt], acc[mt][nt], 0, 0, 0);
        __syncthreads();
    }

#pragma unroll
    for (int mt = 0; mt < 4; ++mt) {
#pragma unroll
        for (int i = 0; i < 4; ++i) {
            int r = wr * 64 + mt * 16 + quad * 4 + i;
            int slot = slotArr[r];
            if (slot < 0) continue;
            float g = gates[slot];
            int tok = slot >> 1;
#pragma unroll
            for (int nt = 0; nt < 4; ++nt) {
                int c = n0 + wc * 64 + nt * 16 + lrow;
                atomicAdd(&out[(size_t)tok * EMB + c], g * acc[mt][nt][i]);
            }
        }
    }
}

extern "C" void kernel_launch(void* const* d_in, const int* in_sizes, int n_in,
                              void* d_out, int out_size, void* d_ws, size_t ws_size,
                              hipStream_t stream) {
    const float* x = (const float*)d_in[0];
    const float* wrout = (const float*)d_in[1];
    const float* w1 = (const float*)d_in[2];
    const float* w3 = (const float*)d_in[3];
    const float* w2 = (const float*)d_in[4];
    float* out = (float*)d_out;

    char* ws = (char*)d_ws;
    const size_t SW = (size_t)N_EXPERTS * EMB * HID * 2;
    const size_t SX = (size_t)NTOK * EMB * 2;
    const size_t SH = (size_t)NSLOT * HID * 2;
    const size_t SMETA = 256 + (size_t)N_EXPERTS * TLIST * 4 + (size_t)NSLOT * 4 + (size_t)NTOK * 4;
    const size_t NEEDED = 3 * SW + SX + SH + SMETA;
    if (ws_size < NEEDED) return;

    unsigned short* w1T = (unsigned short*)(ws);
    unsigned short* w3T = (unsigned short*)(ws + SW);
    unsigned short* w2T = (unsigned short*)(ws + 2 * SW);
    unsigned short* xbf = (unsigned short*)(ws + 3 * SW);
    unsigned short* hbuf = (unsigned short*)(ws + 3 * SW + SX);
    char* meta = ws + 3 * SW + SX + SH;
    int* counts = (int*)meta;
    int* lists = (int*)(meta + 256);
    float* gates = (float*)(meta + 256 + (size_t)N_EXPERTS * TLIST * 4);
    int* sel = (int*)(meta + 256 + (size_t)N_EXPERTS * TLIST * 4 + (size_t)NSLOT * 4);

    // one launch for all three weight transposes (w1:z 0-7, w3:z 8-15, w2:z 16-23)
    transpose_cvt_all<<<dim3(HID / 64, EMB / 64, 3 * N_EXPERTS), 256, 0, stream>>>(
        w1, w3, w2, w1T, w3T, w2T);

    zero_out<<<NTOK * EMB / 4 / 256, 256, 0, stream>>>(out);

    router_kernel<<<NTOK, 64, 0, stream>>>(x, wrout, xbf, sel, gates);
    build_lists<<<N_EXPERTS, 256, 0, stream>>>(sel, counts, lists);

    gemm1_kernel<<<dim3(HID / 64, NTOK / 128, N_EXPERTS), 256, 0, stream>>>(
        xbf, w1T, w3T, hbuf, counts, lists);
    gemm2_kernel<<<dim3(EMB / 128, NTOK / 128, N_EXPERTS), 256, 0, stream>>>(
        hbuf, w2T, out, counts, lists, gates);
}